// Round 1
// baseline (841.073 us; speedup 1.0000x reference)
//
#include <hip/hip_runtime.h>
#include <math.h>

#define T_LEN 6000
#define BATCH 512
#define NCH 8
#define NROWS (BATCH*NCH)   // 4096
#define FILT 256
#define F_BINS 129
#define NSEG 45
#define SEG_STEP 128
#define CF (NCH*F_BINS)     // 1032
#define REG_EPS 1e-7f

// ---------------- Kernel A: row centering (x - mean over T) ----------------
__global__ __launch_bounds__(256) void center_kernel(const float* __restrict__ x,
                                                     float* __restrict__ xc) {
  int rc = blockIdx.x;
  const float4* xr = (const float4*)(x + (size_t)rc * T_LEN);
  float4* xo = (float4*)(xc + (size_t)rc * T_LEN);
  int tid = threadIdx.x;
  float s = 0.f;
  for (int i = tid; i < T_LEN/4; i += 256) {
    float4 v = xr[i];
    s += v.x + v.y + v.z + v.w;
  }
  #pragma unroll
  for (int off = 32; off >= 1; off >>= 1) s += __shfl_down(s, off);
  __shared__ float wsum[4];
  if ((tid & 63) == 0) wsum[tid >> 6] = s;
  __syncthreads();
  float mean = (wsum[0] + wsum[1] + wsum[2] + wsum[3]) * (1.f / T_LEN);
  for (int i = tid; i < T_LEN/4; i += 256) {
    float4 v = xr[i];
    v.x -= mean; v.y -= mean; v.z -= mean; v.w -= mean;
    xo[i] = v;
  }
}

// ---------------- Kernel B: Welch PSD ----------------
// One block (256 threads) per row. 45 segments, per-segment detrend,
// radix-2 DIT FFT (256) in LDS, accumulate |F|^2 for bins 0..128.
// Note: per-segment mean removal absorbs the row mean, so raw x is fine.
__global__ __launch_bounds__(256) void psd_kernel(const float* __restrict__ x,
                                                  float* __restrict__ psd) {
  int rc = blockIdx.x;
  int t = threadIdx.x;
  const float* xr = x + (size_t)rc * T_LEN;
  __shared__ float sre[256], sim[256];
  __shared__ float twr[128], twi[128];
  __shared__ float wsum[4];
  if (t < 128) {
    float ang = -6.283185307179586f * (float)t / 256.f;
    twr[t] = cosf(ang);
    twi[t] = sinf(ang);
  }
  float acc = 0.f;
  unsigned rev = __brev((unsigned)t) >> 24;   // 8-bit bit reverse
  for (int sgi = 0; sgi < NSEG; ++sgi) {
    float v = xr[sgi * SEG_STEP + t];
    float ssum = v;
    #pragma unroll
    for (int off = 32; off >= 1; off >>= 1) ssum += __shfl_down(ssum, off);
    if ((t & 63) == 0) wsum[t >> 6] = ssum;
    __syncthreads();
    v -= (wsum[0] + wsum[1] + wsum[2] + wsum[3]) * (1.f / 256.f);
    sre[rev] = v;
    sim[rev] = 0.f;
    __syncthreads();
    #pragma unroll
    for (int s = 1; s <= 8; ++s) {
      const int half = 1 << (s - 1);
      if (t < 128) {
        int j = t & (half - 1);
        int i1 = ((t >> (s - 1)) << s) + j;
        int i2 = i1 + half;
        int p = j << (8 - s);
        float c = twr[p], sn = twi[p];
        float xr2 = sre[i2], xi2 = sim[i2];
        float tr = c * xr2 - sn * xi2;
        float ti = c * xi2 + sn * xr2;
        float ar = sre[i1], ai = sim[i1];
        sre[i2] = ar - tr; sim[i2] = ai - ti;
        sre[i1] = ar + tr; sim[i1] = ai + ti;
      }
      __syncthreads();
    }
    if (t < F_BINS) acc += sre[t] * sre[t] + sim[t] * sim[t];
    __syncthreads();   // protect sre/sim (and wsum) before next segment
  }
  if (t < F_BINS) {
    float p = acc * (1.f / (256.f * (float)NSEG));
    if (t >= 1 && t <= 127) p *= 2.f;   // one-sided doubling, not DC/Nyquist
    psd[(size_t)rc * F_BINS + t] = p + REG_EPS;
  }
}

// ---------------- Kernel C: barycenter over batch ----------------
// bary[c,f] = (sum_b sqrt(psd[b,c,f]) / 129)^2 ; one block per (c,f)
__global__ __launch_bounds__(256) void bary_kernel(const float* __restrict__ psd,
                                                   float* __restrict__ bary) {
  int cf = blockIdx.x;     // 0..1031  (== c*129+f since CF = 1032)
  int tid = threadIdx.x;
  float s = sqrtf(psd[(size_t)tid * CF + cf]) +
            sqrtf(psd[(size_t)(tid + 256) * CF + cf]);
  #pragma unroll
  for (int off = 32; off >= 1; off >>= 1) s += __shfl_down(s, off);
  __shared__ float wsum[4];
  if ((tid & 63) == 0) wsum[tid >> 6] = s;
  __syncthreads();
  if (tid == 0) {
    float tot = (wsum[0] + wsum[1] + wsum[2] + wsum[3]) * (1.f / (float)F_BINS);
    bary[cf] = tot * tot;
  }
}

// ---------------- Kernel D: filter H = flip(fftshift(irfft(D,256))) ----------------
// D real => h = irfft(D) is real-even; H[k] = h[|k-127|],
// h[n] = (D0 + (-1)^n D128 + 2*sum_{k=1}^{127} Dk cos(2pi k n/256)) / 256
__global__ __launch_bounds__(256) void filt_kernel(const float* __restrict__ psd,
                                                   const float* __restrict__ bary,
                                                   float* __restrict__ H) {
  int rc = blockIdx.x;
  int c = rc & (NCH - 1);
  int t = threadIdx.x;
  __shared__ float ctab[256];
  __shared__ float dv[F_BINS];
  __shared__ float hv[F_BINS];
  ctab[t] = cosf((float)t * (6.283185307179586f / 256.f));
  if (t < F_BINS)
    dv[t] = sqrtf(bary[c * F_BINS + t] / psd[(size_t)rc * F_BINS + t]);
  __syncthreads();
  if (t < F_BINS) {
    float acc = 0.f;
    for (int k = 1; k <= 127; ++k) acc += dv[k] * ctab[(k * t) & 255];
    float val = dv[0] + ((t & 1) ? -dv[128] : dv[128]) + 2.f * acc;
    hv[t] = val * (1.f / 256.f);
  }
  __syncthreads();
  int idx = t - 127; if (idx < 0) idx = -idx;
  H[(size_t)rc * 256 + t] = hv[idx];
}

// ---------------- Kernel E: depthwise 'same' conv ----------------
// y[t] = sum_k xc[t-127+k] * H[k]  (zero padded)
#define TILE_OUT 2048
#define HALO 255
__global__ __launch_bounds__(256) void conv_kernel(const float* __restrict__ xc,
                                                   const float* __restrict__ H,
                                                   float* __restrict__ y) {
  int rc = blockIdx.x / 3;
  int tile = blockIdx.x % 3;
  int t0 = tile * TILE_OUT;
  int tid = threadIdx.x;
  __shared__ __align__(16) float xs[TILE_OUT + 256];   // 2304 (pad past halo)
  __shared__ __align__(16) float Hs[256];
  const float* xr = xc + (size_t)rc * T_LEN;
  Hs[tid] = H[(size_t)rc * 256 + tid];
  #pragma unroll
  for (int j = tid; j < TILE_OUT + 256; j += 256) {
    int g = t0 - 127 + j;
    xs[j] = (g >= 0 && g < T_LEN) ? xr[g] : 0.f;
  }
  __syncthreads();
  int o = tid * 8;
  int tg = t0 + o;
  if (tg >= T_LEN) return;    // 6000 % 8 == 0: whole thread in or out
  float acc[8] = {0,0,0,0,0,0,0,0};
  float w[12];
  #pragma unroll
  for (int i = 0; i < 12; ++i) w[i] = xs[o + i];
  const float4* Hs4 = (const float4*)Hs;
  #pragma unroll
  for (int kg = 0; kg < 64; ++kg) {
    float4 h4 = Hs4[kg];
    #pragma unroll
    for (int i = 0; i < 8; ++i) acc[i] = fmaf(w[i],   h4.x, acc[i]);
    #pragma unroll
    for (int i = 0; i < 8; ++i) acc[i] = fmaf(w[i+1], h4.y, acc[i]);
    #pragma unroll
    for (int i = 0; i < 8; ++i) acc[i] = fmaf(w[i+2], h4.z, acc[i]);
    #pragma unroll
    for (int i = 0; i < 8; ++i) acc[i] = fmaf(w[i+3], h4.w, acc[i]);
    if (kg < 63) {
      #pragma unroll
      for (int i = 0; i < 8; ++i) w[i] = w[i+4];
      float4 nx = *(const float4*)&xs[o + kg*4 + 12];
      w[8] = nx.x; w[9] = nx.y; w[10] = nx.z; w[11] = nx.w;
    }
  }
  float* yr = y + (size_t)rc * T_LEN;
  *(float4*)&yr[tg]   = make_float4(acc[0], acc[1], acc[2], acc[3]);
  *(float4*)&yr[tg+4] = make_float4(acc[4], acc[5], acc[6], acc[7]);
}

extern "C" void kernel_launch(void* const* d_in, const int* in_sizes, int n_in,
                              void* d_out, int out_size, void* d_ws, size_t ws_size,
                              hipStream_t stream) {
  const float* x = (const float*)d_in[0];
  float* out = (float*)d_out;
  float* xc   = (float*)d_ws;                          // 24,576,000 f
  float* psd  = xc + (size_t)NROWS * T_LEN;            //    528,384 f
  float* bary = psd + (size_t)NROWS * F_BINS;          //      1,032 f
  float* H    = bary + CF;                             //  1,048,576 f
  center_kernel<<<NROWS, 256, 0, stream>>>(x, xc);
  psd_kernel<<<NROWS, 256, 0, stream>>>(x, psd);
  bary_kernel<<<CF, 256, 0, stream>>>(psd, bary);
  filt_kernel<<<NROWS, 256, 0, stream>>>(psd, bary, H);
  conv_kernel<<<NROWS * 3, 256, 0, stream>>>(xc, H, out);
}

// Round 2
// 507.965 us; speedup vs baseline: 1.6558x; 1.6558x over previous
//
#include <hip/hip_runtime.h>
#include <math.h>

#define T_LEN 6000
#define NROWS 4096          // B*C = 512*8
#define NCH 8
#define F_BINS 129
#define NSEG 45
#define CF (NCH*F_BINS)     // 1032
#define REG_EPS 1e-7f

// ---------------- Kernel B: Welch PSD + row mean ----------------
// One block per row. 23 iterations; threads 0-127 run the FFT of segment 2*it,
// threads 128-255 the FFT of segment 2*it+1 (45th segment: group 0 only).
// Per-segment detrend absorbs the row mean, so raw x is correct here.
// Byproduct: full row mean (even segments tile [0,5887] contiguously + tail).
__global__ __launch_bounds__(256) void psd_kernel(const float* __restrict__ x,
                                                  float* __restrict__ psd,
                                                  float* __restrict__ means) {
  int rc = blockIdx.x;
  int t = threadIdx.x;
  int grp = t >> 7;        // 0 or 1: which FFT this thread works on
  int lt  = t & 127;
  const float* xr = x + (size_t)rc * T_LEN;
  __shared__ float sre[2][256], sim[2][256];
  __shared__ float twr[128], twi[128];
  __shared__ float wsum[4];
  __shared__ float tail_ws[4];
  if (t < 128) {
    float ang = -6.283185307179586f * (float)t * (1.f / 256.f);
    twr[t] = cosf(ang);
    twi[t] = sinf(ang);
  }
  // tail of the row (5888..5999) for the row mean
  {
    float tv = (t < 112) ? xr[5888 + t] : 0.f;
    #pragma unroll
    for (int off = 32; off >= 1; off >>= 1) tv += __shfl_down(tv, off);
    if ((t & 63) == 0) tail_ws[t >> 6] = tv;   // read only at the very end
  }
  float acc = 0.f, acc128 = 0.f, rowacc = 0.f;
  unsigned rev = __brev((unsigned)lt) >> 24;   // 8-bit reversal of lt (even)
  for (int it = 0; it < 23; ++it) {
    int seg = 2 * it + grp;
    bool active = (seg < NSEG);
    float v0 = 0.f, v1 = 0.f;
    if (active) {
      v0 = xr[seg * 128 + lt];
      v1 = xr[seg * 128 + lt + 128];
    }
    float ssum = v0 + v1;
    #pragma unroll
    for (int off = 32; off >= 1; off >>= 1) ssum += __shfl_down(ssum, off);
    if ((t & 63) == 0) wsum[t >> 6] = ssum;
    __syncthreads();
    // group 0 = waves 0,1 ; group 1 = waves 2,3
    float mean = (wsum[2 * grp] + wsum[2 * grp + 1]) * (1.f / 256.f);
    if (t == 0) rowacc += wsum[0] + wsum[1];   // even segments tile [0,5887]
    if (active) {
      sre[grp][rev]     = v0 - mean;
      sre[grp][rev | 1] = v1 - mean;
      sim[grp][rev]     = 0.f;
      sim[grp][rev | 1] = 0.f;
    }
    __syncthreads();
    #pragma unroll
    for (int s = 1; s <= 8; ++s) {
      if (active) {
        const int half = 1 << (s - 1);
        int j = lt & (half - 1);
        int i1 = ((lt >> (s - 1)) << s) + j;
        int i2 = i1 + half;
        int p = j << (8 - s);
        float c = twr[p], sn = twi[p];
        float br = sre[grp][i2], bi = sim[grp][i2];
        float tr = c * br - sn * bi;
        float ti = c * bi + sn * br;
        float ar = sre[grp][i1], ai = sim[grp][i1];
        sre[grp][i2] = ar - tr; sim[grp][i2] = ai - ti;
        sre[grp][i1] = ar + tr; sim[grp][i1] = ai + ti;
      }
      __syncthreads();
    }
    if (active) {
      acc += sre[grp][lt] * sre[grp][lt] + sim[grp][lt] * sim[grp][lt];
      if (lt == 0)
        acc128 += sre[grp][128] * sre[grp][128] + sim[grp][128] * sim[grp][128];
    }
    __syncthreads();   // protect sre/sim/wsum before next iteration
  }
  // combine the two groups' accumulators
  sre[grp][lt] = acc;
  if (lt == 0) sim[grp][0] = acc128;
  __syncthreads();
  if (t < F_BINS) {
    float a = (t < 128) ? (sre[0][t] + sre[1][t]) : (sim[0][0] + sim[1][0]);
    float p = a * (1.f / (256.f * (float)NSEG));
    if (t >= 1 && t <= 127) p *= 2.f;          // one-sided, not DC/Nyquist
    psd[(size_t)rc * F_BINS + t] = p + REG_EPS;
  }
  if (t == 0)
    means[rc] = (rowacc + tail_ws[0] + tail_ws[1] + tail_ws[2] + tail_ws[3]) *
                (1.f / (float)T_LEN);
}

// ---------------- Kernel C: barycenter over batch ----------------
__global__ __launch_bounds__(256) void bary_kernel(const float* __restrict__ psd,
                                                   float* __restrict__ bary) {
  int cf = blockIdx.x;     // 0..1031 (== c*129+f)
  int tid = threadIdx.x;
  float s = sqrtf(psd[(size_t)tid * CF + cf]) +
            sqrtf(psd[(size_t)(tid + 256) * CF + cf]);
  #pragma unroll
  for (int off = 32; off >= 1; off >>= 1) s += __shfl_down(s, off);
  __shared__ float wsum[4];
  if ((tid & 63) == 0) wsum[tid >> 6] = s;
  __syncthreads();
  if (tid == 0) {
    float tot = (wsum[0] + wsum[1] + wsum[2] + wsum[3]) * (1.f / (float)F_BINS);
    bary[cf] = tot * tot;
  }
}

// ---------------- Kernel D: filter H = flip(fftshift(irfft(D,256))) ----------------
// D real => h real-even; H[k] = h[|k-127|],
// h[n] = (D0 + (-1)^n D128 + 2*sum_{k=1}^{127} Dk cos(2pi k n/256)) / 256
__global__ __launch_bounds__(256) void filt_kernel(const float* __restrict__ psd,
                                                   const float* __restrict__ bary,
                                                   float* __restrict__ H) {
  int rc = blockIdx.x;
  int c = rc & (NCH - 1);
  int t = threadIdx.x;
  __shared__ float ctab[256];
  __shared__ float dv[F_BINS];
  __shared__ float hv[F_BINS];
  ctab[t] = cosf((float)t * (6.283185307179586f / 256.f));
  if (t < F_BINS)
    dv[t] = sqrtf(bary[c * F_BINS + t] / psd[(size_t)rc * F_BINS + t]);
  __syncthreads();
  if (t < F_BINS) {
    float acc = 0.f;
    for (int k = 1; k <= 127; ++k) acc += dv[k] * ctab[(k * t) & 255];
    float val = dv[0] + ((t & 1) ? -dv[128] : dv[128]) + 2.f * acc;
    hv[t] = val * (1.f / 256.f);
  }
  __syncthreads();
  int idx = t - 127; if (idx < 0) idx = -idx;
  H[(size_t)rc * 256 + t] = hv[idx];
}

// ---------------- Kernel E: depthwise 'same' conv, fused centering ----------------
// y[t] = sum_k (x[t-127+k]-mean) * H[k], zero-padded outside [0,T).
// 4 consecutive outputs per thread -> lane LDS stride 16B -> conflict-free b128.
#define CTILE 1024
__global__ __launch_bounds__(256) void conv_kernel(const float* __restrict__ x,
                                                   const float* __restrict__ means,
                                                   const float* __restrict__ H,
                                                   float* __restrict__ y) {
  int rc = blockIdx.x / 6;
  int tile = blockIdx.x % 6;
  int t0 = tile * CTILE;
  int tid = threadIdx.x;
  __shared__ __align__(16) float xs[CTILE + 256];   // 1280 (need 1279)
  __shared__ __align__(16) float Hs[256];
  const float* xr = x + (size_t)rc * T_LEN;
  float mean = means[rc];
  Hs[tid] = H[(size_t)rc * 256 + tid];
  #pragma unroll
  for (int j = tid; j < CTILE + 256; j += 256) {
    int g = t0 - 127 + j;
    xs[j] = (g >= 0 && g < T_LEN) ? (xr[g] - mean) : 0.f;
  }
  __syncthreads();
  int o = tid * 4;
  int tg = t0 + o;
  if (tg >= T_LEN) return;         // 6000 % 4 == 0: clean thread boundary
  float acc[4] = {0.f, 0.f, 0.f, 0.f};
  float w[8];
  {
    float4 wa = *(const float4*)&xs[o];
    float4 wb = *(const float4*)&xs[o + 4];
    w[0] = wa.x; w[1] = wa.y; w[2] = wa.z; w[3] = wa.w;
    w[4] = wb.x; w[5] = wb.y; w[6] = wb.z; w[7] = wb.w;
  }
  const float4* Hs4 = (const float4*)Hs;
  const float4* xs4 = (const float4*)xs;
  #pragma unroll 4
  for (int kg = 0; kg < 64; ++kg) {
    float4 h4 = Hs4[kg];            // wave-uniform -> broadcast
    #pragma unroll
    for (int i = 0; i < 4; ++i) {
      acc[i] = fmaf(w[i],     h4.x, acc[i]);
      acc[i] = fmaf(w[i + 1], h4.y, acc[i]);
      acc[i] = fmaf(w[i + 2], h4.z, acc[i]);
      acc[i] = fmaf(w[i + 3], h4.w, acc[i]);
    }
    if (kg < 63) {
      #pragma unroll
      for (int i = 0; i < 4; ++i) w[i] = w[i + 4];
      float4 nx = xs4[tid + kg + 2];   // consecutive lanes -> consecutive blocks
      w[4] = nx.x; w[5] = nx.y; w[6] = nx.z; w[7] = nx.w;
    }
  }
  float* yr = y + (size_t)rc * T_LEN;
  *(float4*)&yr[tg] = make_float4(acc[0], acc[1], acc[2], acc[3]);
}

extern "C" void kernel_launch(void* const* d_in, const int* in_sizes, int n_in,
                              void* d_out, int out_size, void* d_ws, size_t ws_size,
                              hipStream_t stream) {
  const float* x = (const float*)d_in[0];
  float* out = (float*)d_out;
  float* psd   = (float*)d_ws;                         //   528,384 f
  float* bary  = psd + (size_t)NROWS * F_BINS;         //     1,032 f
  float* H     = bary + CF;                            // 1,048,576 f
  float* means = H + (size_t)NROWS * 256;              //     4,096 f
  psd_kernel<<<NROWS, 256, 0, stream>>>(x, psd, means);
  bary_kernel<<<CF, 256, 0, stream>>>(psd, bary);
  filt_kernel<<<NROWS, 256, 0, stream>>>(psd, bary, H);
  conv_kernel<<<NROWS * 6, 256, 0, stream>>>(x, means, H, out);
}

// Round 3
// 300.393 us; speedup vs baseline: 2.7999x; 1.6910x over previous
//
#include <hip/hip_runtime.h>
#include <math.h>

#define T_LEN 6000
#define NROWS 4096          // B*C = 512*8
#define NCH 8
#define F_BINS 129
#define NSEG 45
#define CF (NCH*F_BINS)     // 1032
#define REG_EPS 1e-7f

// ---------------- Kernel B: Welch PSD + row mean (register FFT, no barriers) ----------------
// One block = 4 waves; wave w handles segment-pairs j = w, w+4, ... (23 pairs total:
// j=0..21 pack segments (2j,2j+1) as z=a+ib; j=22 is segment 44 alone, b=0).
// DIF radix-2, positions idx=r*64+lane; stages 128,64 in-lane; 32..1 via shfl_xor.
// No detrend needed: mean-removal only affects bin 0, which we overwrite with REG_EPS.
// |A[k]|^2+|B[k]|^2 = (|Z[k]|^2+|Z[256-k]|^2)/2 -> accumulate |Z|^2 per POSITION in regs.
__global__ __launch_bounds__(256) void psd_kernel(const float* __restrict__ x,
                                                  float* __restrict__ psd,
                                                  float* __restrict__ means) {
  int rc = blockIdx.x;
  int tid = threadIdx.x;
  int lane = tid & 63;
  int w = tid >> 6;
  const float* xr = x + (size_t)rc * T_LEN;

  // ---- lane-constant twiddles (W_256^e = exp(-2*pi*i*e/256)) ----
  const float W0 = -6.283185307179586f / 256.f;
  float c1, s1, c2, s2;
  __sincosf(W0 * (float)lane, &s1, &c1);          // W^lane   (stage 128)
  __sincosf(W0 * (float)(2 * lane), &s2, &c2);    // W^{2lane} (stage 64)
  float cd[5], sd[5], sg[6];
  #pragma unroll
  for (int st = 0; st < 5; ++st) {                // d = 32,16,8,4,2
    int d = 32 >> st;
    int hi = lane & d;
    float e = (float)((lane & (d - 1)) * (128 / d));
    float ss, cc;
    __sincosf(W0 * e, &ss, &cc);
    cd[st] = hi ? cc : 1.f;
    sd[st] = hi ? ss : 0.f;
    sg[st] = hi ? -1.f : 1.f;
  }
  sg[5] = (lane & 1) ? -1.f : 1.f;                // d = 1 (no twiddle)

  float acc[4] = {0.f, 0.f, 0.f, 0.f};
  float psum = 0.f;

  for (int i = 0; i < 6; ++i) {
    int j = w + 4 * i;
    if (j < 23) {
      // load 6 contiguous chunks: a = c0..c3 (seg 2j), b = c2..c5 (seg 2j+1)
      float c[6];
      int base = 256 * j + lane;
      #pragma unroll
      for (int m = 0; m < 4; ++m) c[m] = xr[base + 64 * m];
      if (j < 22) { c[4] = xr[base + 256]; c[5] = xr[base + 320]; }
      else        { c[4] = 0.f;            c[5] = 0.f; }
      psum += c[0] + c[1] + c[2] + c[3];          // even segs tile [0,5887]
      float zr[4], zi[4];
      #pragma unroll
      for (int r = 0; r < 4; ++r) { zr[r] = c[r]; zi[r] = c[r + 2]; }

      // stage d=128: pairs (0,2),(1,3); twiddle W^lane on z2, W^{lane+64}=(s1,-c1) on z3
      {
        float ar = zr[0] + zr[2], ai = zi[0] + zi[2];
        float ur = zr[0] - zr[2], ui = zi[0] - zi[2];
        zr[0] = ar; zi[0] = ai;
        zr[2] = ur * c1 - ui * s1; zi[2] = ur * s1 + ui * c1;
        float br = zr[1] + zr[3], bi = zi[1] + zi[3];
        float vr = zr[1] - zr[3], vi = zi[1] - zi[3];
        zr[1] = br; zi[1] = bi;
        zr[3] = vr * s1 + vi * c1; zi[3] = vi * s1 - vr * c1;
      }
      // stage d=64: pairs (0,1),(2,3); twiddle W^{2lane}
      {
        float ar = zr[0] + zr[1], ai = zi[0] + zi[1];
        float ur = zr[0] - zr[1], ui = zi[0] - zi[1];
        zr[0] = ar; zi[0] = ai;
        zr[1] = ur * c2 - ui * s2; zi[1] = ur * s2 + ui * c2;
        float br = zr[2] + zr[3], bi = zi[2] + zi[3];
        float vr = zr[2] - zr[3], vi = zi[2] - zi[3];
        zr[2] = br; zi[2] = bi;
        zr[3] = vr * c2 - vi * s2; zi[3] = vr * s2 + vi * c2;
      }
      // stages d=32,16,8,4,2 (cross-lane, twiddled)
      #pragma unroll
      for (int st = 0; st < 5; ++st) {
        int d = 32 >> st;
        float cc = cd[st], ss = sd[st], sn = sg[st];
        #pragma unroll
        for (int r = 0; r < 4; ++r) {
          float pr = __shfl_xor(zr[r], d);
          float pi = __shfl_xor(zi[r], d);
          float tr = fmaf(sn, zr[r], pr);
          float ti = fmaf(sn, zi[r], pi);
          zr[r] = tr * cc - ti * ss;
          zi[r] = tr * ss + ti * cc;
        }
      }
      // stage d=1 (no twiddle)
      #pragma unroll
      for (int r = 0; r < 4; ++r) {
        float pr = __shfl_xor(zr[r], 1);
        float pi = __shfl_xor(zi[r], 1);
        zr[r] = fmaf(sg[5], zr[r], pr);
        zi[r] = fmaf(sg[5], zi[r], pi);
      }
      // accumulate |Z|^2 per position (frequency = br8(position), lane-constant)
      #pragma unroll
      for (int r = 0; r < 4; ++r) {
        acc[r] = fmaf(zr[r], zr[r], acc[r]);
        acc[r] = fmaf(zi[r], zi[r], acc[r]);
      }
    }
  }

  // row-mean: wave 0 adds the tail [5888,5999]
  if (w == 0) {
    float tv = xr[5888 + lane];
    if (lane < 48) tv += xr[5952 + lane];
    psum += tv;
  }
  #pragma unroll
  for (int off = 32; off >= 1; off >>= 1) psum += __shfl_xor(psum, off);

  __shared__ float accb[4][256];
  __shared__ float rsum[4];
  unsigned rev6 = __brev((unsigned)lane) >> 26;
  #pragma unroll
  for (int r = 0; r < 4; ++r) {
    int br2 = (r == 1) ? 2 : ((r == 2) ? 1 : r);
    accb[w][br2 + 4 * rev6] = acc[r];             // frequency index = br8(r*64+lane)
  }
  if (lane == 0) rsum[w] = psum;
  __syncthreads();

  if (tid < F_BINS) {
    float v = 0.f;
    #pragma unroll
    for (int w2 = 0; w2 < 4; ++w2) v += accb[w2][tid];
    if (tid >= 1 && tid <= 127) {
      #pragma unroll
      for (int w2 = 0; w2 < 4; ++w2) v += accb[w2][256 - tid];
    }
    // bins 1..127: (|Z_k|^2+|Z_{256-k}|^2)/2 * 2(one-sided) /(256*45) = v/11520
    // bin 128: |Z_128|^2 /(256*45) = v/11520 (same constant)
    float p = (tid == 0) ? 0.f : v * (1.f / 11520.f);
    psd[(size_t)rc * F_BINS + tid] = p + REG_EPS;
  }
  if (tid == 0)
    means[rc] = (rsum[0] + rsum[1] + rsum[2] + rsum[3]) * (1.f / (float)T_LEN);
}

// ---------------- Kernel C: barycenter over batch ----------------
__global__ __launch_bounds__(256) void bary_kernel(const float* __restrict__ psd,
                                                   float* __restrict__ bary) {
  int cf = blockIdx.x;     // 0..1031 (== c*129+f)
  int tid = threadIdx.x;
  float s = sqrtf(psd[(size_t)tid * CF + cf]) +
            sqrtf(psd[(size_t)(tid + 256) * CF + cf]);
  #pragma unroll
  for (int off = 32; off >= 1; off >>= 1) s += __shfl_down(s, off);
  __shared__ float wsum[4];
  if ((tid & 63) == 0) wsum[tid >> 6] = s;
  __syncthreads();
  if (tid == 0) {
    float tot = (wsum[0] + wsum[1] + wsum[2] + wsum[3]) * (1.f / (float)F_BINS);
    bary[cf] = tot * tot;
  }
}

// ---------------- Kernel D: filter H = flip(fftshift(irfft(D,256))) ----------------
// h[n] = (D0 + (-1)^n D128 + 2*sum_{k=1}^{127} Dk cos(2pi k n/256))/256; H[t]=h[|t-127|]
__global__ __launch_bounds__(256) void filt_kernel(const float* __restrict__ psd,
                                                   const float* __restrict__ bary,
                                                   float* __restrict__ H) {
  int rc = blockIdx.x;
  int c = rc & (NCH - 1);
  int t = threadIdx.x;
  __shared__ float dv[F_BINS];
  __shared__ float hv[F_BINS];
  if (t < F_BINS)
    dv[t] = sqrtf(bary[c * F_BINS + t] / psd[(size_t)rc * F_BINS + t]);
  __syncthreads();
  if (t < F_BINS) {
    // incremental rotation: cos(2*pi*k*t/256) via complex recurrence (no LDS gather)
    float ct, st;
    __sincosf(6.283185307179586f * (float)t * (1.f / 256.f), &st, &ct);
    float cr = ct, ci = st;
    float acc = 0.f;
    for (int k = 1; k <= 127; ++k) {
      acc = fmaf(dv[k], cr, acc);
      float nr = cr * ct - ci * st;
      ci = cr * st + ci * ct;
      cr = nr;
    }
    float val = dv[0] + ((t & 1) ? -dv[128] : dv[128]) + 2.f * acc;
    hv[t] = val * (1.f / 256.f);
  }
  __syncthreads();
  int idx = t - 127; if (idx < 0) idx = -idx;
  H[(size_t)rc * 256 + t] = hv[idx];
}

// ---------------- Kernel E: depthwise 'same' conv, fused centering ----------------
// 8 outputs/thread; xs stored XOR-swizzled (float f -> f ^ (((f>>6)&1)<<2), i.e.
// float4 j -> j ^ ((j>>4)&1)) so stride-2-float4 reads are bank-conflict-free.
#define CTILE 2048
#define LDJ(j) xs4[(j) ^ (((j) >> 4) & 1)]
__global__ __launch_bounds__(256) void conv_kernel(const float* __restrict__ x,
                                                   const float* __restrict__ means,
                                                   const float* __restrict__ H,
                                                   float* __restrict__ y) {
  int rc = blockIdx.x / 3;
  int tile = blockIdx.x % 3;
  int t0 = tile * CTILE;
  int tid = threadIdx.x;
  __shared__ __align__(16) float xs[CTILE + 256 + 16];
  __shared__ __align__(16) float Hs[256];
  const float* xr = x + (size_t)rc * T_LEN;
  float mean = means[rc];
  Hs[tid] = H[(size_t)rc * 256 + tid];
  #pragma unroll
  for (int f = tid; f < CTILE + 256; f += 256) {
    int g = t0 - 127 + f;
    float v = (g >= 0 && g < T_LEN) ? (xr[g] - mean) : 0.f;
    xs[f ^ (((f >> 6) & 1) << 2)] = v;
  }
  __syncthreads();
  int o = tid * 8;
  int tg = t0 + o;
  if (tg >= T_LEN) return;       // 1904 = 238*8: clean thread boundary on tile 2
  const float4* xs4 = (const float4*)xs;
  const float4* Hs4 = (const float4*)Hs;
  float acc[8] = {0,0,0,0,0,0,0,0};
  float w[12];
  {
    float4 A = LDJ(2 * tid);
    float4 B = LDJ(2 * tid + 1);
    float4 C = LDJ(2 * tid + 2);
    w[0]=A.x; w[1]=A.y; w[2]=A.z; w[3]=A.w;
    w[4]=B.x; w[5]=B.y; w[6]=B.z; w[7]=B.w;
    w[8]=C.x; w[9]=C.y; w[10]=C.z; w[11]=C.w;
  }
  #pragma unroll 4
  for (int kg = 0; kg < 64; ++kg) {
    float4 h4 = Hs4[kg];                 // wave-uniform -> broadcast
    #pragma unroll
    for (int i = 0; i < 8; ++i) {
      acc[i] = fmaf(w[i],     h4.x, acc[i]);
      acc[i] = fmaf(w[i + 1], h4.y, acc[i]);
      acc[i] = fmaf(w[i + 2], h4.z, acc[i]);
      acc[i] = fmaf(w[i + 3], h4.w, acc[i]);
    }
    if (kg < 63) {
      #pragma unroll
      for (int i = 0; i < 8; ++i) w[i] = w[i + 4];
      float4 nx = LDJ(2 * tid + kg + 3);
      w[8] = nx.x; w[9] = nx.y; w[10] = nx.z; w[11] = nx.w;
    }
  }
  float* yr = y + (size_t)rc * T_LEN;
  *(float4*)&yr[tg]     = make_float4(acc[0], acc[1], acc[2], acc[3]);
  *(float4*)&yr[tg + 4] = make_float4(acc[4], acc[5], acc[6], acc[7]);
}

extern "C" void kernel_launch(void* const* d_in, const int* in_sizes, int n_in,
                              void* d_out, int out_size, void* d_ws, size_t ws_size,
                              hipStream_t stream) {
  const float* x = (const float*)d_in[0];
  float* out = (float*)d_out;
  float* psd   = (float*)d_ws;                         //   528,384 f
  float* bary  = psd + (size_t)NROWS * F_BINS;         //     1,032 f
  float* H     = bary + CF;                            // 1,048,576 f
  float* means = H + (size_t)NROWS * 256;              //     4,096 f
  psd_kernel<<<NROWS, 256, 0, stream>>>(x, psd, means);
  bary_kernel<<<CF, 256, 0, stream>>>(psd, bary);
  filt_kernel<<<NROWS, 256, 0, stream>>>(psd, bary, H);
  conv_kernel<<<NROWS * 3, 256, 0, stream>>>(x, means, H, out);
}

// Round 5
// 279.699 us; speedup vs baseline: 3.0071x; 1.0740x over previous
//
#include <hip/hip_runtime.h>
#include <math.h>

#define T_LEN 6000
#define NROWS 4096          // B*C = 512*8
#define NCH 8
#define F_BINS 129
#define NSEG 45
#define CF (NCH*F_BINS)     // 1032
#define REG_EPS 1e-7f

// ---------------- Kernel B: Welch PSD + row mean (register FFT, no barriers) ----------------
// One block = 4 waves; wave w handles segment-pairs j = w, w+4, ... (23 pairs total:
// j=0..21 pack segments (2j,2j+1) as z=a+ib; j=22 is segment 44 alone, b=0).
// DIF radix-2, positions idx=r*64+lane; stages 128,64 in-lane; 32..1 via shfl_xor.
// No detrend needed: mean-removal only affects bin 0, which we overwrite with REG_EPS.
// |A[k]|^2+|B[k]|^2 = (|Z[k]|^2+|Z[256-k]|^2)/2 -> accumulate |Z|^2 per POSITION in regs.
__global__ __launch_bounds__(256) void psd_kernel(const float* __restrict__ x,
                                                  float* __restrict__ psd,
                                                  float* __restrict__ means) {
  int rc = blockIdx.x;
  int tid = threadIdx.x;
  int lane = tid & 63;
  int w = tid >> 6;
  const float* xr = x + (size_t)rc * T_LEN;

  // ---- lane-constant twiddles (W_256^e = exp(-2*pi*i*e/256)) ----
  const float W0 = -6.283185307179586f / 256.f;
  float c1, s1, c2, s2;
  __sincosf(W0 * (float)lane, &s1, &c1);          // W^lane   (stage 128)
  __sincosf(W0 * (float)(2 * lane), &s2, &c2);    // W^{2lane} (stage 64)
  float cd[5], sd[5], sg[6];
  #pragma unroll
  for (int st = 0; st < 5; ++st) {                // d = 32,16,8,4,2
    int d = 32 >> st;
    int hi = lane & d;
    float e = (float)((lane & (d - 1)) * (128 / d));
    float ss, cc;
    __sincosf(W0 * e, &ss, &cc);
    cd[st] = hi ? cc : 1.f;
    sd[st] = hi ? ss : 0.f;
    sg[st] = hi ? -1.f : 1.f;
  }
  sg[5] = (lane & 1) ? -1.f : 1.f;                // d = 1 (no twiddle)

  float acc[4] = {0.f, 0.f, 0.f, 0.f};
  float psum = 0.f;

  for (int i = 0; i < 6; ++i) {
    int j = w + 4 * i;
    if (j < 23) {
      // load 6 contiguous chunks: a = c0..c3 (seg 2j), b = c2..c5 (seg 2j+1)
      float c[6];
      int base = 256 * j + lane;
      #pragma unroll
      for (int m = 0; m < 4; ++m) c[m] = xr[base + 64 * m];
      if (j < 22) { c[4] = xr[base + 256]; c[5] = xr[base + 320]; }
      else        { c[4] = 0.f;            c[5] = 0.f; }
      psum += c[0] + c[1] + c[2] + c[3];          // even segs tile [0,5887]
      float zr[4], zi[4];
      #pragma unroll
      for (int r = 0; r < 4; ++r) { zr[r] = c[r]; zi[r] = c[r + 2]; }

      // stage d=128: pairs (0,2),(1,3); twiddle W^lane on z2, W^{lane+64}=(s1,-c1) on z3
      {
        float ar = zr[0] + zr[2], ai = zi[0] + zi[2];
        float ur = zr[0] - zr[2], ui = zi[0] - zi[2];
        zr[0] = ar; zi[0] = ai;
        zr[2] = ur * c1 - ui * s1; zi[2] = ur * s1 + ui * c1;
        float br = zr[1] + zr[3], bi = zi[1] + zi[3];
        float vr = zr[1] - zr[3], vi = zi[1] - zi[3];
        zr[1] = br; zi[1] = bi;
        zr[3] = vr * s1 + vi * c1; zi[3] = vi * s1 - vr * c1;
      }
      // stage d=64: pairs (0,1),(2,3); twiddle W^{2lane}
      {
        float ar = zr[0] + zr[1], ai = zi[0] + zi[1];
        float ur = zr[0] - zr[1], ui = zi[0] - zi[1];
        zr[0] = ar; zi[0] = ai;
        zr[1] = ur * c2 - ui * s2; zi[1] = ur * s2 + ui * c2;
        float br = zr[2] + zr[3], bi = zi[2] + zi[3];
        float vr = zr[2] - zr[3], vi = zi[2] - zi[3];
        zr[2] = br; zi[2] = bi;
        zr[3] = vr * c2 - vi * s2; zi[3] = vr * s2 + vi * c2;
      }
      // stages d=32,16,8,4,2 (cross-lane, twiddled)
      #pragma unroll
      for (int st = 0; st < 5; ++st) {
        int d = 32 >> st;
        float cc = cd[st], ss = sd[st], sn = sg[st];
        #pragma unroll
        for (int r = 0; r < 4; ++r) {
          float pr = __shfl_xor(zr[r], d);
          float pi = __shfl_xor(zi[r], d);
          float tr = fmaf(sn, zr[r], pr);
          float ti = fmaf(sn, zi[r], pi);
          zr[r] = tr * cc - ti * ss;
          zi[r] = tr * ss + ti * cc;
        }
      }
      // stage d=1 (no twiddle)
      #pragma unroll
      for (int r = 0; r < 4; ++r) {
        float pr = __shfl_xor(zr[r], 1);
        float pi = __shfl_xor(zi[r], 1);
        zr[r] = fmaf(sg[5], zr[r], pr);
        zi[r] = fmaf(sg[5], zi[r], pi);
      }
      // accumulate |Z|^2 per position (frequency = br8(position), lane-constant)
      #pragma unroll
      for (int r = 0; r < 4; ++r) {
        acc[r] = fmaf(zr[r], zr[r], acc[r]);
        acc[r] = fmaf(zi[r], zi[r], acc[r]);
      }
    }
  }

  // row-mean: wave 0 adds the tail [5888,5999]
  if (w == 0) {
    float tv = xr[5888 + lane];
    if (lane < 48) tv += xr[5952 + lane];
    psum += tv;
  }
  #pragma unroll
  for (int off = 32; off >= 1; off >>= 1) psum += __shfl_xor(psum, off);

  __shared__ float accb[4][256];
  __shared__ float rsum[4];
  unsigned rev6 = __brev((unsigned)lane) >> 26;
  #pragma unroll
  for (int r = 0; r < 4; ++r) {
    int br2 = (r == 1) ? 2 : ((r == 2) ? 1 : r);
    accb[w][br2 + 4 * rev6] = acc[r];             // frequency index = br8(r*64+lane)
  }
  if (lane == 0) rsum[w] = psum;
  __syncthreads();

  if (tid < F_BINS) {
    float v = 0.f;
    #pragma unroll
    for (int w2 = 0; w2 < 4; ++w2) v += accb[w2][tid];
    if (tid >= 1 && tid <= 127) {
      #pragma unroll
      for (int w2 = 0; w2 < 4; ++w2) v += accb[w2][256 - tid];
    }
    float p = (tid == 0) ? 0.f : v * (1.f / 11520.f);
    psd[(size_t)rc * F_BINS + tid] = p + REG_EPS;
  }
  if (tid == 0)
    means[rc] = (rsum[0] + rsum[1] + rsum[2] + rsum[3]) * (1.f / (float)T_LEN);
}

// ---------------- Kernel C: barycenter over batch ----------------
__global__ __launch_bounds__(256) void bary_kernel(const float* __restrict__ psd,
                                                   float* __restrict__ bary) {
  int cf = blockIdx.x;     // 0..1031 (== c*129+f)
  int tid = threadIdx.x;
  float s = sqrtf(psd[(size_t)tid * CF + cf]) +
            sqrtf(psd[(size_t)(tid + 256) * CF + cf]);
  #pragma unroll
  for (int off = 32; off >= 1; off >>= 1) s += __shfl_down(s, off);
  __shared__ float wsum[4];
  if ((tid & 63) == 0) wsum[tid >> 6] = s;
  __syncthreads();
  if (tid == 0) {
    float tot = (wsum[0] + wsum[1] + wsum[2] + wsum[3]) * (1.f / (float)F_BINS);
    bary[cf] = tot * tot;
  }
}

// ---------------- Kernel D: filter H = flip(fftshift(irfft(D,256))) ----------------
// h[n] = (D0 + (-1)^n D128 + 2*sum_{k=1}^{127} Dk cos(2pi k n/256))/256; H[t]=h[|t-127|]
__global__ __launch_bounds__(256) void filt_kernel(const float* __restrict__ psd,
                                                   const float* __restrict__ bary,
                                                   float* __restrict__ H) {
  int rc = blockIdx.x;
  int c = rc & (NCH - 1);
  int t = threadIdx.x;
  __shared__ float dv[F_BINS];
  __shared__ float hv[F_BINS];
  if (t < F_BINS)
    dv[t] = sqrtf(bary[c * F_BINS + t] / psd[(size_t)rc * F_BINS + t]);
  __syncthreads();
  if (t < F_BINS) {
    float ct, st;
    __sincosf(6.283185307179586f * (float)t * (1.f / 256.f), &st, &ct);
    float cr = ct, ci = st;
    float acc = 0.f;
    for (int k = 1; k <= 127; ++k) {
      acc = fmaf(dv[k], cr, acc);
      float nr = cr * ct - ci * st;
      ci = cr * st + ci * ct;
      cr = nr;
    }
    float val = dv[0] + ((t & 1) ? -dv[128] : dv[128]) + 2.f * acc;
    hv[t] = val * (1.f / 256.f);
  }
  __syncthreads();
  int idx = t - 127; if (idx < 0) idx = -idx;
  H[(size_t)rc * 256 + t] = hv[idx];
}

// ---------------- Kernel E: depthwise 'same' conv, fused centering ----------------
// One block (384 thr) per row; thread computes 16 consecutive outputs (375*16=6000).
// NO divergent return: all 384 threads run the whole loop (tid>=375 works on the
// zero-padded LDS tail and discards its result) so v_readlane always reads lanes
// that executed the H loads. Only the final store is predicated.
// Whole padded row in LDS (xs[f] = x[f-127]-mean, zeros outside), 3-bit quad
// swizzle q^=(q>>3)&7: stride-4-quad b128 reads cover all 8 bank-groups evenly
// (= inherent minimum, same as contiguous); stays within aligned-8 quad blocks.
// H kept in 4 VGPRs/wave (H[64r+lane]); per-tap broadcast via v_readlane (no LDS).
// kg loop fully unrolled: circular window W[20] with static mod-20 indices.
#define XS_FLOATS 6400          // 1600 quads: covers reads up to quad 1599 (tid 383)
#define SWZQ(q) ((q) ^ (((q) >> 3) & 7))
__global__ __launch_bounds__(384) void conv_kernel(const float* __restrict__ x,
                                                   const float* __restrict__ means,
                                                   const float* __restrict__ Hg,
                                                   float* __restrict__ y) {
  int rc = blockIdx.x;
  int tid = threadIdx.x;
  int lane = tid & 63;
  __shared__ __align__(16) float xs[XS_FLOATS];
  const float* xr = x + (size_t)rc * T_LEN;
  float mean = means[rc];
  // stage padded, centered row (zeros beyond [127,127+T)) with swizzled writes
  for (int f = tid; f < XS_FLOATS; f += 384) {
    int g = f - 127;
    float v = (g >= 0 && g < T_LEN) ? (xr[g] - mean) : 0.f;
    int q = f >> 2;
    xs[(SWZQ(q) << 2) | (f & 3)] = v;
  }
  // H row into 4 VGPRs per lane: hr[r] = H[64r+lane] (all lanes, no divergence)
  const float* Hrow = Hg + (size_t)rc * 256;
  float h0 = Hrow[lane], h1 = Hrow[64 + lane], h2 = Hrow[128 + lane], h3 = Hrow[192 + lane];
  __syncthreads();

  const float4* xs4 = (const float4*)xs;
  int qb = tid * 4;
  float acc[16];
  #pragma unroll
  for (int i = 0; i < 16; ++i) acc[i] = 0.f;
  float W[20];
  #pragma unroll
  for (int c0 = 0; c0 < 5; ++c0) {
    int q = qb + c0;
    float4 v = xs4[SWZQ(q)];
    W[4 * c0]     = v.x; W[4 * c0 + 1] = v.y;
    W[4 * c0 + 2] = v.z; W[4 * c0 + 3] = v.w;
  }
  #pragma unroll 64
  for (int kg = 0; kg < 64; ++kg) {
    float4 nx;
    if (kg < 63) {                       // prefetch next quad early
      int qn = qb + kg + 5;
      nx = xs4[SWZQ(qn)];
    }
    float hsrc = (kg < 16) ? h0 : (kg < 32) ? h1 : (kg < 48) ? h2 : h3;
    #pragma unroll
    for (int c = 0; c < 4; ++c) {        // tap k = 4*kg + c
      float h = __int_as_float(
          __builtin_amdgcn_readlane(__float_as_int(hsrc), 4 * (kg & 15) + c));
      #pragma unroll
      for (int i = 0; i < 16; ++i)
        acc[i] = fmaf(W[(4 * kg + c + i) % 20], h, acc[i]);
    }
    if (kg < 63) {                       // retire 4 oldest slots, install prefetch
      W[(4 * kg)     % 20] = nx.x;
      W[(4 * kg + 1) % 20] = nx.y;
      W[(4 * kg + 2) % 20] = nx.z;
      W[(4 * kg + 3) % 20] = nx.w;
    }
  }
  if (tid < 375) {                       // 375*16 = 6000; discard helper threads
    float* yr = y + (size_t)rc * T_LEN + tid * 16;
    #pragma unroll
    for (int s = 0; s < 4; ++s)
      *(float4*)&yr[4 * s] = make_float4(acc[4*s], acc[4*s+1], acc[4*s+2], acc[4*s+3]);
  }
}

extern "C" void kernel_launch(void* const* d_in, const int* in_sizes, int n_in,
                              void* d_out, int out_size, void* d_ws, size_t ws_size,
                              hipStream_t stream) {
  const float* x = (const float*)d_in[0];
  float* out = (float*)d_out;
  float* psd   = (float*)d_ws;                         //   528,384 f
  float* bary  = psd + (size_t)NROWS * F_BINS;         //     1,032 f
  float* H     = bary + CF;                            // 1,048,576 f
  float* means = H + (size_t)NROWS * 256;              //     4,096 f
  psd_kernel<<<NROWS, 256, 0, stream>>>(x, psd, means);
  bary_kernel<<<CF, 256, 0, stream>>>(psd, bary);
  filt_kernel<<<NROWS, 256, 0, stream>>>(psd, bary, H);
  conv_kernel<<<NROWS, 384, 0, stream>>>(x, means, H, out);
}

// Round 6
// 142.756 us; speedup vs baseline: 5.8917x; 1.9593x over previous
//
#include <hip/hip_runtime.h>
#include <math.h>

#define T_LEN 6000
#define NROWS 4096          // B*C = 512*8
#define NCH 8
#define F_BINS 129
#define NSEG 45
#define CF (NCH*F_BINS)     // 1032
#define REG_EPS 1e-7f

// ---------------- Kernel B: Welch PSD + row mean (register FFT, no barriers) ----------------
// (unchanged from round 5 — passing)
__global__ __launch_bounds__(256) void psd_kernel(const float* __restrict__ x,
                                                  float* __restrict__ psd,
                                                  float* __restrict__ means) {
  int rc = blockIdx.x;
  int tid = threadIdx.x;
  int lane = tid & 63;
  int w = tid >> 6;
  const float* xr = x + (size_t)rc * T_LEN;

  const float W0 = -6.283185307179586f / 256.f;
  float c1, s1, c2, s2;
  __sincosf(W0 * (float)lane, &s1, &c1);
  __sincosf(W0 * (float)(2 * lane), &s2, &c2);
  float cd[5], sd[5], sg[6];
  #pragma unroll
  for (int st = 0; st < 5; ++st) {
    int d = 32 >> st;
    int hi = lane & d;
    float e = (float)((lane & (d - 1)) * (128 / d));
    float ss, cc;
    __sincosf(W0 * e, &ss, &cc);
    cd[st] = hi ? cc : 1.f;
    sd[st] = hi ? ss : 0.f;
    sg[st] = hi ? -1.f : 1.f;
  }
  sg[5] = (lane & 1) ? -1.f : 1.f;

  float acc[4] = {0.f, 0.f, 0.f, 0.f};
  float psum = 0.f;

  for (int i = 0; i < 6; ++i) {
    int j = w + 4 * i;
    if (j < 23) {
      float c[6];
      int base = 256 * j + lane;
      #pragma unroll
      for (int m = 0; m < 4; ++m) c[m] = xr[base + 64 * m];
      if (j < 22) { c[4] = xr[base + 256]; c[5] = xr[base + 320]; }
      else        { c[4] = 0.f;            c[5] = 0.f; }
      psum += c[0] + c[1] + c[2] + c[3];
      float zr[4], zi[4];
      #pragma unroll
      for (int r = 0; r < 4; ++r) { zr[r] = c[r]; zi[r] = c[r + 2]; }
      {
        float ar = zr[0] + zr[2], ai = zi[0] + zi[2];
        float ur = zr[0] - zr[2], ui = zi[0] - zi[2];
        zr[0] = ar; zi[0] = ai;
        zr[2] = ur * c1 - ui * s1; zi[2] = ur * s1 + ui * c1;
        float br = zr[1] + zr[3], bi = zi[1] + zi[3];
        float vr = zr[1] - zr[3], vi = zi[1] - zi[3];
        zr[1] = br; zi[1] = bi;
        zr[3] = vr * s1 + vi * c1; zi[3] = vi * s1 - vr * c1;
      }
      {
        float ar = zr[0] + zr[1], ai = zi[0] + zi[1];
        float ur = zr[0] - zr[1], ui = zi[0] - zi[1];
        zr[0] = ar; zi[0] = ai;
        zr[1] = ur * c2 - ui * s2; zi[1] = ur * s2 + ui * c2;
        float br = zr[2] + zr[3], bi = zi[2] + zi[3];
        float vr = zr[2] - zr[3], vi = zi[2] - zi[3];
        zr[2] = br; zi[2] = bi;
        zr[3] = vr * c2 - vi * s2; zi[3] = vr * s2 + vi * c2;
      }
      #pragma unroll
      for (int st = 0; st < 5; ++st) {
        int d = 32 >> st;
        float cc = cd[st], ss = sd[st], sn = sg[st];
        #pragma unroll
        for (int r = 0; r < 4; ++r) {
          float pr = __shfl_xor(zr[r], d);
          float pi = __shfl_xor(zi[r], d);
          float tr = fmaf(sn, zr[r], pr);
          float ti = fmaf(sn, zi[r], pi);
          zr[r] = tr * cc - ti * ss;
          zi[r] = tr * ss + ti * cc;
        }
      }
      #pragma unroll
      for (int r = 0; r < 4; ++r) {
        float pr = __shfl_xor(zr[r], 1);
        float pi = __shfl_xor(zi[r], 1);
        zr[r] = fmaf(sg[5], zr[r], pr);
        zi[r] = fmaf(sg[5], zi[r], pi);
      }
      #pragma unroll
      for (int r = 0; r < 4; ++r) {
        acc[r] = fmaf(zr[r], zr[r], acc[r]);
        acc[r] = fmaf(zi[r], zi[r], acc[r]);
      }
    }
  }

  if (w == 0) {
    float tv = xr[5888 + lane];
    if (lane < 48) tv += xr[5952 + lane];
    psum += tv;
  }
  #pragma unroll
  for (int off = 32; off >= 1; off >>= 1) psum += __shfl_xor(psum, off);

  __shared__ float accb[4][256];
  __shared__ float rsum[4];
  unsigned rev6 = __brev((unsigned)lane) >> 26;
  #pragma unroll
  for (int r = 0; r < 4; ++r) {
    int br2 = (r == 1) ? 2 : ((r == 2) ? 1 : r);
    accb[w][br2 + 4 * rev6] = acc[r];
  }
  if (lane == 0) rsum[w] = psum;
  __syncthreads();

  if (tid < F_BINS) {
    float v = 0.f;
    #pragma unroll
    for (int w2 = 0; w2 < 4; ++w2) v += accb[w2][tid];
    if (tid >= 1 && tid <= 127) {
      #pragma unroll
      for (int w2 = 0; w2 < 4; ++w2) v += accb[w2][256 - tid];
    }
    float p = (tid == 0) ? 0.f : v * (1.f / 11520.f);
    psd[(size_t)rc * F_BINS + tid] = p + REG_EPS;
  }
  if (tid == 0)
    means[rc] = (rsum[0] + rsum[1] + rsum[2] + rsum[3]) * (1.f / (float)T_LEN);
}

// ---------------- Kernel C: barycenter over batch (unchanged) ----------------
__global__ __launch_bounds__(256) void bary_kernel(const float* __restrict__ psd,
                                                   float* __restrict__ bary) {
  int cf = blockIdx.x;
  int tid = threadIdx.x;
  float s = sqrtf(psd[(size_t)tid * CF + cf]) +
            sqrtf(psd[(size_t)(tid + 256) * CF + cf]);
  #pragma unroll
  for (int off = 32; off >= 1; off >>= 1) s += __shfl_down(s, off);
  __shared__ float wsum[4];
  if ((tid & 63) == 0) wsum[tid >> 6] = s;
  __syncthreads();
  if (tid == 0) {
    float tot = (wsum[0] + wsum[1] + wsum[2] + wsum[3]) * (1.f / (float)F_BINS);
    bary[cf] = tot * tot;
  }
}

// ---------------- Kernel D: filter H (unchanged) ----------------
__global__ __launch_bounds__(256) void filt_kernel(const float* __restrict__ psd,
                                                   const float* __restrict__ bary,
                                                   float* __restrict__ H) {
  int rc = blockIdx.x;
  int c = rc & (NCH - 1);
  int t = threadIdx.x;
  __shared__ float dv[F_BINS];
  __shared__ float hv[F_BINS];
  if (t < F_BINS)
    dv[t] = sqrtf(bary[c * F_BINS + t] / psd[(size_t)rc * F_BINS + t]);
  __syncthreads();
  if (t < F_BINS) {
    float ct, st;
    __sincosf(6.283185307179586f * (float)t * (1.f / 256.f), &st, &ct);
    float cr = ct, ci = st;
    float acc = 0.f;
    for (int k = 1; k <= 127; ++k) {
      acc = fmaf(dv[k], cr, acc);
      float nr = cr * ct - ci * st;
      ci = cr * st + ci * ct;
      cr = nr;
    }
    float val = dv[0] + ((t & 1) ? -dv[128] : dv[128]) + 2.f * acc;
    hv[t] = val * (1.f / 256.f);
  }
  __syncthreads();
  int idx = t - 127; if (idx < 0) idx = -idx;
  H[(size_t)rc * 256 + t] = hv[idx];
}

// ---------------- Kernel E: depthwise conv as per-row im2col MFMA GEMM ----------------
// Y[m][n] = y[16m+n] = sum_k A[m][k]*B[k][n], A[m][k]=xpad[16m+k] (xpad[p]=x[p-127]-mean,
// zero outside), B[k][n]=H[k-n] (0 if k-n not in [0,256)). M=384 (375 real), K=288 (272
// real), N=16. Per row: 24 M-tiles x 9 K-steps of mfma_f32_16x16x32_f16; 6 waves x 4 tiles.
// Both A and B frags are 8 CONTIGUOUS k per lane with the same placement (any within-K
// hardware permutation cancels). C/D: col=lane&15, row=4*(lane>>4)+reg (HW-verified).
typedef _Float16 half8 __attribute__((ext_vector_type(8)));
typedef float f32x4 __attribute__((ext_vector_type(4)));
#define XH_N 6528
#define BSTRIDE 296          // f16 row stride of B panel (37 quads, odd -> banks spread)
__global__ __launch_bounds__(384, 1) void conv_kernel(const float* __restrict__ x,
                                                      const float* __restrict__ means,
                                                      const float* __restrict__ Hg,
                                                      float* __restrict__ y) {
  int rc = blockIdx.x;
  int tid = threadIdx.x;
  int lane = tid & 63;
  int w = tid >> 6;
  __shared__ __align__(16) _Float16 xh[XH_N];
  __shared__ __align__(16) _Float16 Bp[16 * BSTRIDE];
  const float* xr = x + (size_t)rc * T_LEN;
  const float* Hrow = Hg + (size_t)rc * 256;
  float mean = means[rc];
  // A source: padded, centered row in f16 (zeros outside [127,6127))
  for (int f = tid; f < XH_N; f += 384) {
    int g = f - 127;
    float v = (g >= 0 && g < T_LEN) ? (xr[g] - mean) : 0.f;
    xh[f] = (_Float16)v;
  }
  // B panel: Bp[n*BSTRIDE+k] = H[k-n] for k in [0,288) (k in [288,296) never read)
  for (int idx = tid; idx < 16 * 288; idx += 384) {
    int n = idx / 288;
    int k = idx - n * 288;
    int s = k - n;
    float v = (s >= 0 && s < 256) ? Hrow[s] : 0.f;
    Bp[n * BSTRIDE + k] = (_Float16)v;
  }
  __syncthreads();

  int l15 = lane & 15, l4 = lane >> 4;
  f32x4 acc0 = {0.f,0.f,0.f,0.f}, acc1 = {0.f,0.f,0.f,0.f};
  f32x4 acc2 = {0.f,0.f,0.f,0.f}, acc3 = {0.f,0.f,0.f,0.f};
  const _Float16* bbase = &Bp[BSTRIDE * l15 + 8 * l4];
  const _Float16* abase = &xh[16 * l15 + 8 * l4 + 1024 * w];   // mt0 = 4*w
  #pragma unroll
  for (int kk = 0; kk < 9; ++kk) {
    half8 b = *(const half8*)(bbase + 32 * kk);
    half8 a0 = *(const half8*)(abase + 32 * kk);
    half8 a1 = *(const half8*)(abase + 256 + 32 * kk);
    half8 a2 = *(const half8*)(abase + 512 + 32 * kk);
    half8 a3 = *(const half8*)(abase + 768 + 32 * kk);
    acc0 = __builtin_amdgcn_mfma_f32_16x16x32_f16(a0, b, acc0, 0, 0, 0);
    acc1 = __builtin_amdgcn_mfma_f32_16x16x32_f16(a1, b, acc1, 0, 0, 0);
    acc2 = __builtin_amdgcn_mfma_f32_16x16x32_f16(a2, b, acc2, 0, 0, 0);
    acc3 = __builtin_amdgcn_mfma_f32_16x16x32_f16(a3, b, acc3, 0, 0, 0);
  }
  // store: for tile mt, lane writes y[256*mt + 16*(4*l4+j) + l15], j=0..3
  float* yr = y + (size_t)rc * T_LEN;
  #pragma unroll
  for (int i = 0; i < 4; ++i) {
    f32x4 a = (i == 0) ? acc0 : (i == 1) ? acc1 : (i == 2) ? acc2 : acc3;
    int mt = 4 * w + i;
    #pragma unroll
    for (int j = 0; j < 4; ++j) {
      int m = 16 * mt + 4 * l4 + j;
      if (m < 375) yr[16 * m + l15] = a[j];
    }
  }
}

extern "C" void kernel_launch(void* const* d_in, const int* in_sizes, int n_in,
                              void* d_out, int out_size, void* d_ws, size_t ws_size,
                              hipStream_t stream) {
  const float* x = (const float*)d_in[0];
  float* out = (float*)d_out;
  float* psd   = (float*)d_ws;                         //   528,384 f
  float* bary  = psd + (size_t)NROWS * F_BINS;         //     1,032 f
  float* H     = bary + CF;                            // 1,048,576 f
  float* means = H + (size_t)NROWS * 256;              //     4,096 f
  psd_kernel<<<NROWS, 256, 0, stream>>>(x, psd, means);
  bary_kernel<<<CF, 256, 0, stream>>>(psd, bary);
  filt_kernel<<<NROWS, 256, 0, stream>>>(psd, bary, H);
  conv_kernel<<<NROWS, 384, 0, stream>>>(x, means, H, out);
}

// Round 7
// 125.107 us; speedup vs baseline: 6.7228x; 1.1411x over previous
//
#include <hip/hip_runtime.h>
#include <math.h>

#define T_LEN 6000
#define NROWS 4096          // B*C = 512*8
#define NCH 8
#define F_BINS 129
#define CF (NCH*F_BINS)     // 1032
#define REG_EPS 1e-7f

typedef _Float16 half8 __attribute__((ext_vector_type(8)));
typedef _Float16 half4_t __attribute__((ext_vector_type(4)));
typedef float f32x4 __attribute__((ext_vector_type(4)));

// ---------------- Kernel A: DFT basis (row-independent), Bt[n][k] f16 ----------------
// n<129: cos(2*pi*n*k/256); n>=129: sin(2*pi*(n-128)*k/256). Exact angle reduction
// via (n*k)&255 keeps float sin/cos accurate.
__global__ __launch_bounds__(256) void basis_kernel(_Float16* __restrict__ Bt) {
  int n = blockIdx.x;        // 0..255
  int k = threadIdx.x;       // 0..255
  int m = (n < 129) ? ((n * k) & 255) : (((n - 128) * k) & 255);
  float ang = (float)m * (6.283185307179586f / 256.f);
  float v = (n < 129) ? cosf(ang) : sinf(ang);
  Bt[(n << 8) | k] = (_Float16)v;
}

// ---------------- Kernel B: Welch PSD + row mean via im2col MFMA GEMM ----------------
// Per row: A[m][k]=x[128m+k] (M=48 tiles of 16, m<45 valid; K=256), B[k][n]=DFT basis
// (N=256: cos 0..128, sin 129..255). C[m][n] -> psd[f] = (sum_m Re^2+Im^2) scaled.
// 4 waves x 4 N-tiles; B frags persistent in VGPRs (loaded once per block, 8 rows).
// A staged as f16 in LDS, XOR-swizzled byte^=((byte>>8)&7)<<4 (2 lanes/bank-group).
// Detrend only affects bin 0 -> psd[0]=REG_EPS. Mask m>=45 in the square-accumulate.
#define PSD_ROWS 8
__global__ __launch_bounds__(256, 2) void psd_kernel(const float* __restrict__ x,
                                                     const _Float16* __restrict__ Bt,
                                                     float* __restrict__ psd,
                                                     float* __restrict__ means) {
  int tid = threadIdx.x;
  int lane = tid & 63;
  int w = tid >> 6;          // 0..3
  int l15 = lane & 15, l4 = lane >> 4;
  __shared__ __align__(16) _Float16 xh[6272];
  __shared__ float colsum[256];
  __shared__ float rowm[4];

  // persistent B fragments: nt = 4w+i, lane col n = 16*nt+l15, k = 32*kk+8*l4..+8
  half8 bf[4][8];
  #pragma unroll
  for (int i = 0; i < 4; ++i) {
    const _Float16* bb = Bt + (((16 * (4 * w + i) + l15) << 8) + 8 * l4);
    #pragma unroll
    for (int kk = 0; kk < 8; ++kk)
      bf[i][kk] = *(const half8*)(bb + 32 * kk);
  }

  int r0 = blockIdx.x * PSD_ROWS;
  for (int jr = 0; jr < PSD_ROWS; ++jr) {
    int r = r0 + jr;
    const float* xr = x + (size_t)r * T_LEN;
    // ---- stage row to f16 LDS (swizzled writes), accumulate row sum ----
    float rsum = 0.f;
    #pragma unroll
    for (int j = 0; j < 7; ++j) {
      int c = tid + 256 * j;                    // float4 chunk index
      if (c < 1568) {
        float4 v = (c < 1500) ? ((const float4*)xr)[c]
                              : make_float4(0.f, 0.f, 0.f, 0.f);
        rsum += v.x + v.y + v.z + v.w;
        half4_t h = { (_Float16)v.x, (_Float16)v.y, (_Float16)v.z, (_Float16)v.w };
        int byte = 8 * c;
        byte ^= ((byte >> 8) & 7) << 4;
        *(half4_t*)((char*)xh + byte) = h;
      }
    }
    __syncthreads();                            // (A) stage visible
    // ---- GEMM ----
    f32x4 acc[4][3];
    #pragma unroll
    for (int i = 0; i < 4; ++i)
      #pragma unroll
      for (int mt = 0; mt < 3; ++mt)
        acc[i][mt] = (f32x4){0.f, 0.f, 0.f, 0.f};
    #pragma unroll
    for (int kk = 0; kk < 8; ++kk) {
      half8 a[3];
      #pragma unroll
      for (int mt = 0; mt < 3; ++mt) {
        int ab = 4096 * mt + 256 * l15 + 64 * kk + 16 * l4;
        ab ^= ((ab >> 8) & 7) << 4;
        a[mt] = *(const half8*)((const char*)xh + ab);
      }
      #pragma unroll
      for (int i = 0; i < 4; ++i)
        #pragma unroll
        for (int mt = 0; mt < 3; ++mt)
          acc[i][mt] = __builtin_amdgcn_mfma_f32_16x16x32_f16(a[mt], bf[i][kk],
                                                              acc[i][mt], 0, 0, 0);
    }
    // row-sum reduce (registers only; written to LDS after barrier B)
    #pragma unroll
    for (int off = 32; off >= 1; off >>= 1) rsum += __shfl_xor(rsum, off);
    // per-lane column partials; C/D: row m = 16*mt+4*l4+j, col n = 16*nt+l15
    float s0, s1, s2, s3;
    #pragma unroll
    for (int i = 0; i < 4; ++i) {
      float t = 0.f;
      #pragma unroll
      for (int j = 0; j < 4; ++j) {
        t += acc[i][0][j] * acc[i][0][j];
        t += acc[i][1][j] * acc[i][1][j];
        if (4 * l4 + j < 13) t += acc[i][2][j] * acc[i][2][j];  // mask m>=45
      }
      t += __shfl_xor(t, 16);
      t += __shfl_xor(t, 32);
      if (i == 0) s0 = t; else if (i == 1) s1 = t; else if (i == 2) s2 = t; else s3 = t;
    }
    __syncthreads();                            // (B) xh & prev colsum reads done
    if (l4 == 0) {
      colsum[16 * (4 * w + 0) + l15] = s0;
      colsum[16 * (4 * w + 1) + l15] = s1;
      colsum[16 * (4 * w + 2) + l15] = s2;
      colsum[16 * (4 * w + 3) + l15] = s3;
    }
    if (lane == 0) rowm[w] = rsum;
    __syncthreads();                            // (C)
    if (tid < F_BINS) {
      float v;
      if (tid == 0) v = 0.f;                                    // detrended DC
      else if (tid == 128) v = colsum[128] * (1.f / 11520.f);   // Nyquist, no doubling
      else v = (colsum[tid] + colsum[tid + 128]) * (1.f / 5760.f);
      psd[(size_t)r * F_BINS + tid] = v + REG_EPS;
    }
    if (tid == 0)
      means[r] = (rowm[0] + rowm[1] + rowm[2] + rowm[3]) * (1.f / (float)T_LEN);
  }
}

// ---------------- Kernel C: barycenter over batch (unchanged) ----------------
__global__ __launch_bounds__(256) void bary_kernel(const float* __restrict__ psd,
                                                   float* __restrict__ bary) {
  int cf = blockIdx.x;
  int tid = threadIdx.x;
  float s = sqrtf(psd[(size_t)tid * CF + cf]) +
            sqrtf(psd[(size_t)(tid + 256) * CF + cf]);
  #pragma unroll
  for (int off = 32; off >= 1; off >>= 1) s += __shfl_down(s, off);
  __shared__ float wsum[4];
  if ((tid & 63) == 0) wsum[tid >> 6] = s;
  __syncthreads();
  if (tid == 0) {
    float tot = (wsum[0] + wsum[1] + wsum[2] + wsum[3]) * (1.f / (float)F_BINS);
    bary[cf] = tot * tot;
  }
}

// ---------------- Kernel D: filter H (unchanged) ----------------
__global__ __launch_bounds__(256) void filt_kernel(const float* __restrict__ psd,
                                                   const float* __restrict__ bary,
                                                   float* __restrict__ H) {
  int rc = blockIdx.x;
  int c = rc & (NCH - 1);
  int t = threadIdx.x;
  __shared__ float dv[F_BINS];
  __shared__ float hv[F_BINS];
  if (t < F_BINS)
    dv[t] = sqrtf(bary[c * F_BINS + t] / psd[(size_t)rc * F_BINS + t]);
  __syncthreads();
  if (t < F_BINS) {
    float ct, st;
    __sincosf(6.283185307179586f * (float)t * (1.f / 256.f), &st, &ct);
    float cr = ct, ci = st;
    float acc = 0.f;
    for (int k = 1; k <= 127; ++k) {
      acc = fmaf(dv[k], cr, acc);
      float nr = cr * ct - ci * st;
      ci = cr * st + ci * ct;
      cr = nr;
    }
    float val = dv[0] + ((t & 1) ? -dv[128] : dv[128]) + 2.f * acc;
    hv[t] = val * (1.f / 256.f);
  }
  __syncthreads();
  int idx = t - 127; if (idx < 0) idx = -idx;
  H[(size_t)rc * 256 + t] = hv[idx];
}

// ---------------- Kernel E: depthwise conv as per-row im2col MFMA GEMM (unchanged) ----------------
#define XH_N 6528
#define BSTRIDE 296
__global__ __launch_bounds__(384, 1) void conv_kernel(const float* __restrict__ x,
                                                      const float* __restrict__ means,
                                                      const float* __restrict__ Hg,
                                                      float* __restrict__ y) {
  int rc = blockIdx.x;
  int tid = threadIdx.x;
  int lane = tid & 63;
  int w = tid >> 6;
  __shared__ __align__(16) _Float16 xh[XH_N];
  __shared__ __align__(16) _Float16 Bp[16 * BSTRIDE];
  const float* xr = x + (size_t)rc * T_LEN;
  const float* Hrow = Hg + (size_t)rc * 256;
  float mean = means[rc];
  for (int f = tid; f < XH_N; f += 384) {
    int g = f - 127;
    float v = (g >= 0 && g < T_LEN) ? (xr[g] - mean) : 0.f;
    xh[f] = (_Float16)v;
  }
  for (int idx = tid; idx < 16 * 288; idx += 384) {
    int n = idx / 288;
    int k = idx - n * 288;
    int s = k - n;
    float v = (s >= 0 && s < 256) ? Hrow[s] : 0.f;
    Bp[n * BSTRIDE + k] = (_Float16)v;
  }
  __syncthreads();

  int l15 = lane & 15, l4 = lane >> 4;
  f32x4 acc0 = {0.f,0.f,0.f,0.f}, acc1 = {0.f,0.f,0.f,0.f};
  f32x4 acc2 = {0.f,0.f,0.f,0.f}, acc3 = {0.f,0.f,0.f,0.f};
  const _Float16* bbase = &Bp[BSTRIDE * l15 + 8 * l4];
  const _Float16* abase = &xh[16 * l15 + 8 * l4 + 1024 * w];
  #pragma unroll
  for (int kk = 0; kk < 9; ++kk) {
    half8 b = *(const half8*)(bbase + 32 * kk);
    half8 a0 = *(const half8*)(abase + 32 * kk);
    half8 a1 = *(const half8*)(abase + 256 + 32 * kk);
    half8 a2 = *(const half8*)(abase + 512 + 32 * kk);
    half8 a3 = *(const half8*)(abase + 768 + 32 * kk);
    acc0 = __builtin_amdgcn_mfma_f32_16x16x32_f16(a0, b, acc0, 0, 0, 0);
    acc1 = __builtin_amdgcn_mfma_f32_16x16x32_f16(a1, b, acc1, 0, 0, 0);
    acc2 = __builtin_amdgcn_mfma_f32_16x16x32_f16(a2, b, acc2, 0, 0, 0);
    acc3 = __builtin_amdgcn_mfma_f32_16x16x32_f16(a3, b, acc3, 0, 0, 0);
  }
  float* yr = y + (size_t)rc * T_LEN;
  #pragma unroll
  for (int i = 0; i < 4; ++i) {
    f32x4 a = (i == 0) ? acc0 : (i == 1) ? acc1 : (i == 2) ? acc2 : acc3;
    int mt = 4 * w + i;
    #pragma unroll
    for (int j = 0; j < 4; ++j) {
      int m = 16 * mt + 4 * l4 + j;
      if (m < 375) yr[16 * m + l15] = a[j];
    }
  }
}

extern "C" void kernel_launch(void* const* d_in, const int* in_sizes, int n_in,
                              void* d_out, int out_size, void* d_ws, size_t ws_size,
                              hipStream_t stream) {
  const float* x = (const float*)d_in[0];
  float* out = (float*)d_out;
  float* psd   = (float*)d_ws;                         //   528,384 f
  float* bary  = psd + (size_t)NROWS * F_BINS;         //     1,032 f
  float* H     = bary + CF;                            // 1,048,576 f
  float* means = H + (size_t)NROWS * 256;              //     4,096 f
  _Float16* Bt = (_Float16*)(means + NROWS);           //    65,536 f16 (16B-aligned)
  basis_kernel<<<256, 256, 0, stream>>>(Bt);
  psd_kernel<<<NROWS / PSD_ROWS, 256, 0, stream>>>(x, Bt, psd, means);
  bary_kernel<<<CF, 256, 0, stream>>>(psd, bary);
  filt_kernel<<<NROWS, 256, 0, stream>>>(psd, bary, H);
  conv_kernel<<<NROWS, 384, 0, stream>>>(x, means, H, out);
}